// Round 1
// 190.696 us; speedup vs baseline: 1.0056x; 1.0056x over previous
//
#include <hip/hip_runtime.h>

#define G_SLOTS   8
#define D_OUT     7
#define NODE_DIM  128
#define GLOB_DIM  128
#define HIDDEN    64
#define NEG_VAL   (-1000000000.0f)
#define ROW_H     272            // halves per row; 544 B => uniform 8-per-bank b128
#define H_STRIDE  68             // f32 dwords; H row stride
#define POUT_OFF  4352           // f32 dword offset of pout inside wt (after H's 64*68)

typedef _Float16 half8 __attribute__((ext_vector_type(8)));
typedef float    f32x4 __attribute__((ext_vector_type(4)));

// ---------------- single fused kernel --------------------------------------
// Block: 256 threads = 4 waves, 64 slots = 8 batches.
// Segment starts are computed IN-BLOCK via 9-thread lower_bound on the sorted
// batch[] (replaces the former seg_starts kernel + its dispatch gap).
// xa: [64 m][256 k] f16 (node cols 0..127, glob cols 128..255), row = slot.
// wt: [64 n][256 k] f16 (W1 transposed).  C = X @ W1 via mfma_f32_16x16x32_f16.
// After MFMA (barrier), wt's space is reused: H (f32 [64][68]) at dw 0,
// pout (f32 [4][448]) at dw POUT_OFF — disjoint, both < 8704 dw capacity.
// Barrier-removal proofs (wave-locality):
//  * ballot->gather: gather thread t reads nidxl[t>>2]; its batch is
//    (t>>2)>>3 in {2w,2w+1} = written by the SAME wave w. In-order LDS.
//  * H-write->layer2: wave w writes H[:, 16w..16w+15] (all 64 rows across its
//    lanes); layer-2 thread has partu = t>>6 = w and reads exactly those
//    columns. pout region (dw >= POUT_OFF) disjoint from all H writes.
// NOTE: every per-element epilogue loop MUST cover all 448 elems with 256
// threads — a plain `if (t < 448)` silently drops elems 256..447 (R3/R5-R7 bug).
__global__ __launch_bounds__(256) void fused_mlp_kernel(
        const float* __restrict__ node,
        const float* __restrict__ glob,
        const int* __restrict__ sel,
        const int* __restrict__ batch,
        const int* __restrict__ mmask,
        const float* __restrict__ W1,
        const float* __restrict__ b1,
        const float* __restrict__ W2,
        const float* __restrict__ b2,
        float* __restrict__ out,
        int N, int B) {
    __shared__ __align__(16) _Float16 xa[64 * ROW_H];   // 34816 B
    __shared__ __align__(16) _Float16 wt[64 * ROW_H];   // 34816 B
    __shared__ __align__(16) int starts_l[G_SLOTS + 1];
    __shared__ __align__(16) int nidxl[64];

    int t = threadIdx.x;
    int b0 = (int)blockIdx.x * 8;
    int slot0 = (int)blockIdx.x * 64;

    // ---- epilogue prefetch: mmask + b2 for this thread's 2 elems ----------
    // Issued first so the loads are long retired before the final phase.
    int e1 = t + 256;
    int sl0 = t / D_OUT, d0 = t - sl0 * D_OUT;
    int mm0 = mmask[slot0 * D_OUT + t];
    float b2v0 = b2[d0];
    int sl1 = 0, mm1 = 0; float b2v1 = 0.0f;
    if (e1 < 64 * D_OUT) {
        sl1 = e1 / D_OUT;
        int d1 = e1 - sl1 * D_OUT;
        mm1 = mmask[slot0 * D_OUT + e1];
        b2v1 = b2[d1];
    }

    // ---- segment boundaries: 9-thread lower_bound on sorted batch[] -------
    // 18 dependent probes; upper levels are shared across all blocks -> L1/L2
    // hot. Runs on wave 0 while waves 1-3 proceed with staging below.
    if (t < 9) {
        int target = b0 + t;
        int lo = 0, hi = N;
        while (lo < hi) {
            int mid = (lo + hi) >> 1;
            if (batch[mid] < target) lo = mid + 1; else hi = mid;
        }
        starts_l[t] = lo;     // lower_bound == old seg_starts semantics,
    }                         // incl. empty batches and starts[B] = N

    // ---- stage W1^T as f16: thread (n = t&63, ko8 = (t>>6)*8) ----
    {
        int n = t & 63, ko8 = (t >> 6) * 8;
#pragma unroll
        for (int it = 0; it < 8; ++it) {
            int k0 = it * 32 + ko8;
            half8 hv;
#pragma unroll
            for (int j = 0; j < 8; ++j) {
                hv[j] = (_Float16)W1[(k0 + j) * HIDDEN + n];
            }
            *(half8*)&wt[n * ROW_H + k0] = hv;
        }
    }

    // ---- stage glob into xa cols 128..255: thread (r = t>>2, q = t&3) ----
    {
        int r = t >> 2, q = t & 3;
        const float* gsrc = glob + (size_t)(b0 + (r >> 3)) * GLOB_DIM + q * 32;
        int dst = r * ROW_H + 128 + q * 32;
#pragma unroll
        for (int jj = 0; jj < 4; ++jj) {
            half8 hv;
#pragma unroll
            for (int j = 0; j < 8; ++j) {
                hv[j] = (_Float16)gsrc[jj * 8 + j];
            }
            *(half8*)&xa[dst + jj * 8] = hv;
        }
    }
    __syncthreads();

    // ---- ballot scan: wave w handles batches 2w, 2w+1 ----
    {
        int w = t >> 6, lane = t & 63;
        for (int bi = w * 2; bi < w * 2 + 2; ++bi) {
            int start = starts_l[bi], end = starts_l[bi + 1];
            int found = 0;
            for (int base = start; base < end && found < G_SLOTS; base += 64) {
                int i = base + lane;
                bool s = (i < end) && (sel[i] != 0);
                unsigned long long m = __ballot(s);
                if (s) {
                    int rank = found + __popcll(m & ((1ull << lane) - 1ull));
                    if (rank < G_SLOTS) nidxl[bi * G_SLOTS + rank] = i;
                }
                found += __popcll(m);
            }
            int f = found < G_SLOTS ? found : G_SLOTS;
            if (lane < G_SLOTS - f) nidxl[bi * G_SLOTS + f + lane] = -1;
        }
    }
    // NO barrier: gather below reads only same-wave nidxl entries (proof above)

    // ---- gather node rows into xa cols 0..127 (f16) ----
    {
        int r = t >> 2, q = t & 3;
        int nidx = nidxl[r];
        int dst = r * ROW_H + q * 32;
        if (nidx >= 0) {
            const float* src = node + (size_t)nidx * NODE_DIM + q * 32;
#pragma unroll
            for (int jj = 0; jj < 4; ++jj) {
                half8 hv;
#pragma unroll
                for (int j = 0; j < 8; ++j) {
                    hv[j] = (_Float16)src[jj * 8 + j];
                }
                *(half8*)&xa[dst + jj * 8] = hv;
            }
        } else {
            half8 hz;
#pragma unroll
            for (int j = 0; j < 8; ++j) hz[j] = (_Float16)0.0f;
#pragma unroll
            for (int jj = 0; jj < 4; ++jj) *(half8*)&xa[dst + jj * 8] = hz;
        }
    }
    __syncthreads();

    // ---- MFMA: wave w owns n-tile w. A[m=lane&15][k=quad*8+j]; B likewise ----
    int w = t >> 6, lane = t & 63;
    int col = lane & 15, quad = lane >> 4;
    f32x4 acc0, acc1, acc2, acc3;
    acc0 = 0.0f; acc1 = 0.0f; acc2 = 0.0f; acc3 = 0.0f;
    {
        int nrow = w * 16 + col;
#pragma unroll
        for (int kt = 0; kt < 8; ++kt) {
            half8 bf = *(const half8*)&wt[nrow * ROW_H + kt * 32 + quad * 8];
            half8 a0 = *(const half8*)&xa[(0 * 16 + col) * ROW_H + kt * 32 + quad * 8];
            half8 a1 = *(const half8*)&xa[(1 * 16 + col) * ROW_H + kt * 32 + quad * 8];
            half8 a2 = *(const half8*)&xa[(2 * 16 + col) * ROW_H + kt * 32 + quad * 8];
            half8 a3 = *(const half8*)&xa[(3 * 16 + col) * ROW_H + kt * 32 + quad * 8];
            acc0 = __builtin_amdgcn_mfma_f32_16x16x32_f16(a0, bf, acc0, 0, 0, 0);
            acc1 = __builtin_amdgcn_mfma_f32_16x16x32_f16(a1, bf, acc1, 0, 0, 0);
            acc2 = __builtin_amdgcn_mfma_f32_16x16x32_f16(a2, bf, acc2, 0, 0, 0);
            acc3 = __builtin_amdgcn_mfma_f32_16x16x32_f16(a3, bf, acc3, 0, 0, 0);
        }
    }
    int nh = w * 16 + col;
    float b1v = b1[nh];
    __syncthreads();                  // all waves done reading xa/wt

    // ---- H = relu(C + b1) into wt-space as f32; C/D: col=lane&15, row=quad*4+reg ----
    {
        float* H = (float*)wt;
#pragma unroll
        for (int reg = 0; reg < 4; ++reg) {
            int m0 = quad * 4 + reg;
            H[(m0 +  0) * H_STRIDE + nh] = fmaxf(acc0[reg] + b1v, 0.0f);
            H[(m0 + 16) * H_STRIDE + nh] = fmaxf(acc1[reg] + b1v, 0.0f);
            H[(m0 + 32) * H_STRIDE + nh] = fmaxf(acc2[reg] + b1v, 0.0f);
            H[(m0 + 48) * H_STRIDE + nh] = fmaxf(acc3[reg] + b1v, 0.0f);
        }
    }
    // NO barrier: layer-2 below reads only columns written by its own wave
    // (partu == w), and pout writes are disjoint from all H writes.

    // ---- second layer: thread (sl = t&63) over hidden [partu*16, +16) ----
    {
        const float* H = (const float*)wt;
        float* pout = (float*)wt + POUT_OFF;           // disjoint from H region
        int sl = t & 63;
        int partu = t >> 6;                            // wave-uniform == w
        float p[D_OUT];
#pragma unroll
        for (int d = 0; d < D_OUT; ++d) p[d] = 0.0f;
#pragma unroll
        for (int jj = 0; jj < 4; ++jj) {
            float4 hq = *(const float4*)&H[sl * H_STRIDE + partu * 16 + jj * 4];
            float hv0 = hq.x, hv1 = hq.y, hv2 = hq.z, hv3 = hq.w;
            int n0 = partu * 16 + jj * 4;              // wave-uniform -> scalar loads
#pragma unroll
            for (int d = 0; d < D_OUT; ++d) {
                float s = fmaf(hv0, W2[(n0 + 0) * D_OUT + d], p[d]);
                s = fmaf(hv1, W2[(n0 + 1) * D_OUT + d], s);
                s = fmaf(hv2, W2[(n0 + 2) * D_OUT + d], s);
                s = fmaf(hv3, W2[(n0 + 3) * D_OUT + d], s);
                p[d] = s;
            }
        }
#pragma unroll
        for (int d = 0; d < D_OUT; ++d) pout[partu * 448 + sl * D_OUT + d] = p[d];
    }
    __syncthreads();

    // ---- final reduce + bias + mask + store: 448 elems, 256 threads -------
    // e0 = t (always < 448), e1 = t + 256 (guarded). mmask/b2 prefetched.
    {
        const float* pout = (const float*)wt + POUT_OFF;
        float v0 = pout[t] + pout[448 + t] + pout[896 + t] + pout[1344 + t] + b2v0;
        bool ok0 = (nidxl[sl0] >= 0) && (mm0 != 0);
        out[slot0 * D_OUT + t] = ok0 ? v0 : NEG_VAL;
        if (e1 < 64 * D_OUT) {
            float v1 = pout[e1] + pout[448 + e1] + pout[896 + e1] + pout[1344 + e1] + b2v1;
            bool ok1 = (nidxl[sl1] >= 0) && (mm1 != 0);
            out[slot0 * D_OUT + e1] = ok1 ? v1 : NEG_VAL;
        }
    }
}

extern "C" void kernel_launch(void* const* d_in, const int* in_sizes, int n_in,
                              void* d_out, int out_size, void* d_ws, size_t ws_size,
                              hipStream_t stream) {
    const float* node  = (const float*)d_in[0];   // (N, 128)
    const float* glob  = (const float*)d_in[1];   // (B, 128)
    const int*   sel   = (const int*)d_in[2];     // (N,)
    const int*   batch = (const int*)d_in[3];     // (N,)
    const int*   mmask = (const int*)d_in[4];     // (B, G, D)
    const float* W1    = (const float*)d_in[5];   // (256, 64)
    const float* b1    = (const float*)d_in[6];   // (64,)
    const float* W2    = (const float*)d_in[7];   // (64, 7)
    const float* b2    = (const float*)d_in[8];   // (7,)
    float* out = (float*)d_out;

    int N = in_sizes[3];
    int B = in_sizes[1] / GLOB_DIM;

    fused_mlp_kernel<<<(B * G_SLOTS) / 64, 256, 0, stream>>>(
        node, glob, sel, batch, mmask, W1, b1, W2, b2, out, N, B);
}